// Round 12
// baseline (364.355 us; speedup 1.0000x reference)
//
#include <hip/hip_runtime.h>
#include <hip/hip_bf16.h>

// Problem constants (S=2048, B=2, E=2048, H=32, D=64)
#define S_LEN 2048
#define BATCH 2
#define EMB   2048
#define NH    32
#define HD    64
#define M_ROWS (S_LEN * BATCH)   // 4096
#define QKV_N  (3 * EMB)         // 6144

typedef short bf16x8 __attribute__((ext_vector_type(8)));
typedef float f32x4  __attribute__((ext_vector_type(4)));

__device__ __forceinline__ unsigned short f2bf(float f) {
  unsigned int u = __float_as_uint(f);
  u += 0x7fffu + ((u >> 16) & 1u);       // round-to-nearest-even
  return (unsigned short)(u >> 16);
}
__device__ __forceinline__ float bf2f(unsigned short h) {
  return __uint_as_float(((unsigned int)h) << 16);
}
__device__ __forceinline__ void async_copy16(const void* g, void* lds_d) {
  __builtin_amdgcn_global_load_lds(
      (const __attribute__((address_space(1))) void*)g,
      (__attribute__((address_space(3))) void*)lds_d, 16, 0, 0);
}

#if __has_builtin(__builtin_amdgcn_exp2f)
#define EXP2F(x) __builtin_amdgcn_exp2f(x)
#else
#define EXP2F(x) __expf((x) * 0.6931471805599453f)
#endif

// ---------------- prep: ONE launch for cast + both weight transposes ----------------
// Merging the 3 independent prep kernels into one flat-grid launch removes 2
// inter-launch gaps (R7-measured win). Bodies identical to verified kernels.

#define CAST_BLKS  (M_ROWS * EMB / 4 / 256)          // 8192
#define TCQ_BX     (QKV_N / 64)                      // 96
#define TCQ_BLKS   (TCQ_BX * (EMB / 64))             // 3072
#define TCO_BX     (EMB / 64)                        // 32
#define TCO_BLKS   (TCO_BX * (EMB / 64))             // 1024
#define PREP_BLKS  (CAST_BLKS + TCQ_BLKS + TCO_BLKS) // 12288

__device__ __forceinline__ void transpose_body(
    const float* __restrict__ in, unsigned short* __restrict__ out,
    int R, int C, int bx, int by, int tid) {
  __shared__ unsigned short t[64][65];
  const int bc = bx * 64, br = by * 64;
  const int tx = tid & 63, ty = tid >> 6;   // ty 0..3
  #pragma unroll
  for (int rr = ty; rr < 64; rr += 4)
    t[rr][tx] = f2bf(in[(size_t)(br + rr) * C + bc + tx]);
  __syncthreads();
  #pragma unroll
  for (int rr = ty; rr < 64; rr += 4)
    out[(size_t)(bc + rr) * R + br + tx] = t[tx][rr];
}

__global__ __launch_bounds__(256) void prep_all(
    const float* __restrict__ hidden, unsigned short* __restrict__ hbf,
    const float* __restrict__ qkv_w, unsigned short* __restrict__ qkvwT,
    const float* __restrict__ out_w, unsigned short* __restrict__ outwT) {
  const int bid = blockIdx.x, tid = threadIdx.x;
  if (bid < CAST_BLKS) {
    const int i = bid * 256 + tid;
    float4 v = reinterpret_cast<const float4*>(hidden)[i];
    ushort4 o;
    o.x = f2bf(v.x); o.y = f2bf(v.y); o.z = f2bf(v.z); o.w = f2bf(v.w);
    reinterpret_cast<ushort4*>(hbf)[i] = o;
  } else if (bid < CAST_BLKS + TCQ_BLKS) {
    const int b = bid - CAST_BLKS;
    transpose_body(qkv_w, qkvwT, EMB, QKV_N, b % TCQ_BX, b / TCQ_BX, tid);
  } else {
    const int b = bid - CAST_BLKS - TCQ_BLKS;
    transpose_body(out_w, outwT, EMB, EMB, b % TCO_BX, b / TCO_BX, tid);
  }
}

// ---------------- QKV GEMM (R1-measured-best): 256x128 tile, BK=64, 8 waves,
// triple-buffered LDS, 2 phases/K-tile with counted vmcnt + setprio.
// V-block (which==2) epilogue writes VT[b,h,d,s] DIRECTLY via an LDS
// transpose (tile [128 n][264] shorts, 16B-aligned rows, bank-verified free
// writes / balanced reads) -> transpose_v kernel and Vb buffer eliminated.

constexpr int TILE_SH = 24576;                 // shorts/buffer: A 256x64 + B 128x64
constexpr int GEMM_LDS_BYTES = 3 * TILE_SH * 2; // 147456 B

__global__ __launch_bounds__(512, 2) void gemm_qkv(
    const unsigned short* __restrict__ A,
    const unsigned short* __restrict__ Wt,
    const float* __restrict__ bias,
    unsigned short* __restrict__ Qo,
    unsigned short* __restrict__ Ko,
    unsigned short* __restrict__ VTo) {
  extern __shared__ unsigned short lds[];
  const int tid = threadIdx.x;               // 0..511
  const int n0 = blockIdx.x * 128;
  const int m0 = blockIdx.y * 256;
  const int wave = tid >> 6, lane = tid & 63;
  const int wm = (wave >> 1) * 64, wn = (wave & 1) * 64;   // 4M x 2N waves
  const int lm = lane & 15, lq = lane >> 4;
  const int K = 2048;
  const int NT = K / 64;                     // 32 K-tiles

  const int srow = tid >> 3;                 // 0..63
  const int gch  = (tid & 7) ^ (srow & 7);
  const unsigned short* Ab = A  + (size_t)(m0 + srow) * K + gch * 8;
  const unsigned short* Bb = Wt + (size_t)(n0 + srow) * K + gch * 8;

  auto stA = [&](int bufi, int k0, int rep) {
    async_copy16(Ab + (size_t)rep * 64 * K + k0,
                 lds + (size_t)bufi * TILE_SH + ((size_t)rep * 512 + tid) * 8);
  };
  auto stB = [&](int bufi, int k0, int rep) {
    async_copy16(Bb + (size_t)rep * 64 * K + k0,
                 lds + (size_t)bufi * TILE_SH + 16384 + ((size_t)rep * 512 + tid) * 8);
  };

  f32x4 acc[4][4] = {};

  stA(0, 0, 0); stA(0, 0, 1); stA(0, 0, 2); stA(0, 0, 3); stB(0, 0, 0); stB(0, 0, 1);
  stA(1, 64, 0); stA(1, 64, 1); stA(1, 64, 2); stA(1, 64, 3); stB(1, 64, 0); stB(1, 64, 1);
  asm volatile("s_waitcnt vmcnt(6)" ::: "memory");
  __builtin_amdgcn_s_barrier();

  int cur = 0;
  for (int t = 0; t < NT; t++) {
    const unsigned short* Abuf = lds + (size_t)cur * TILE_SH;
    const unsigned short* Bbuf = Abuf + 16384;
    const int pb = (cur >= 1) ? cur - 1 : 2;   // (cur+2)%3
    const int pk = (t + 2) * 64;
    const bool pre = (t + 2) < NT;

    bf16x8 b[4][2], a[2][2];
    #pragma unroll
    for (int j = 0; j < 4; j++) {
      const int R = wn + j * 16 + lm;
      #pragma unroll
      for (int ks = 0; ks < 2; ks++)
        b[j][ks] = *reinterpret_cast<const bf16x8*>(
            Bbuf + (size_t)R * 64 + (((ks * 4 + lq) ^ (R & 7)) * 8));
    }
    #pragma unroll
    for (int i = 0; i < 2; i++) {
      const int R = wm + i * 16 + lm;
      #pragma unroll
      for (int ks = 0; ks < 2; ks++)
        a[i][ks] = *reinterpret_cast<const bf16x8*>(
            Abuf + (size_t)R * 64 + (((ks * 4 + lq) ^ (R & 7)) * 8));
    }
    if (pre) { stA(pb, pk, 0); stA(pb, pk, 1); stB(pb, pk, 0); }
    __builtin_amdgcn_s_barrier();
    asm volatile("s_waitcnt lgkmcnt(0)" ::: "memory");
    __builtin_amdgcn_s_setprio(1);
    #pragma unroll
    for (int ks = 0; ks < 2; ks++)
      #pragma unroll
      for (int i = 0; i < 2; i++)
        #pragma unroll
        for (int j = 0; j < 4; j++)
          acc[i][j] = __builtin_amdgcn_mfma_f32_16x16x32_bf16(a[i][ks], b[j][ks], acc[i][j], 0, 0, 0);
    __builtin_amdgcn_s_setprio(0);
    __builtin_amdgcn_s_barrier();

    #pragma unroll
    for (int i = 0; i < 2; i++) {
      const int R = wm + (i + 2) * 16 + lm;
      #pragma unroll
      for (int ks = 0; ks < 2; ks++)
        a[i][ks] = *reinterpret_cast<const bf16x8*>(
            Abuf + (size_t)R * 64 + (((ks * 4 + lq) ^ (R & 7)) * 8));
    }
    if (pre) { stA(pb, pk, 2); stA(pb, pk, 3); stB(pb, pk, 1); }
    __builtin_amdgcn_s_barrier();
    asm volatile("s_waitcnt lgkmcnt(0)" ::: "memory");
    __builtin_amdgcn_s_setprio(1);
    #pragma unroll
    for (int ks = 0; ks < 2; ks++)
      #pragma unroll
      for (int i = 0; i < 2; i++)
        #pragma unroll
        for (int j = 0; j < 4; j++)
          acc[i + 2][j] = __builtin_amdgcn_mfma_f32_16x16x32_bf16(a[i][ks], b[j][ks], acc[i + 2][j], 0, 0, 0);
    __builtin_amdgcn_s_setprio(0);
    if (t + 1 < NT) {
      if (pre) asm volatile("s_waitcnt vmcnt(6)" ::: "memory");
      else     asm volatile("s_waitcnt vmcnt(0)" ::: "memory");
      __builtin_amdgcn_s_barrier();
    }
    cur = (cur == 2) ? 0 : cur + 1;
  }

  // epilogue
  const int which = n0 >> 11;   // 0=q 1=k 2=v, uniform per block
  float bv[4];
  #pragma unroll
  for (int j = 0; j < 4; j++) bv[j] = bias[n0 + wn + j * 16 + lm];

  if (which < 2) {
    unsigned short* dst = (which == 0) ? Qo : Ko;
    // RoPE pairs (d, d+32) = (acc[i][j], acc[i][j+2]) for j=0,1 (d = j*16+lm)
    #pragma unroll
    for (int j = 0; j < 2; j++) {
      const int n = n0 + wn + j * 16 + lm;
      const int e = n & (EMB - 1), h = e >> 6, d = e & 63;   // d < 32
      const float invf = EXP2F((float)d * -0.4152410118609203f);  // 10000^(-d/32)
      #pragma unroll
      for (int i = 0; i < 4; i++) {
        #pragma unroll
        for (int r = 0; r < 4; r++) {
          const int m = m0 + wm + i * 16 + lq * 4 + r;
          const int s = m >> 1, b = m & 1;
          const float v1 = acc[i][j][r]     + bv[j];
          const float v2 = acc[i][j + 2][r] + bv[j + 2];
          float sn, cs;
          __sincosf((float)s * invf, &sn, &cs);
          const size_t base = (((size_t)b * NH + h) * S_LEN + s) * HD + d;
          dst[base]      = f2bf(v1 * cs - v2 * sn);
          dst[base + 32] = f2bf(v2 * cs + v1 * sn);
        }
      }
    }
  } else {
    // V: route tile through LDS -> write VT[b,h,d,s] with coalesced s-major stores.
    __syncthreads();                       // K-loop LDS now dead everywhere
    unsigned short* T = lds;
    #pragma unroll
    for (int j = 0; j < 4; j++) {
      const int nl = wn + j * 16 + lm;
      #pragma unroll
      for (int i = 0; i < 4; i++) {
        const int sbase = (wm >> 1) + i * 8 + lq * 2;   // s_local of r=0/1
        #pragma unroll
        for (int r = 0; r < 4; r++)
          T[nl * 264 + (r & 1) * 128 + sbase + (r >> 1)] = f2bf(acc[i][j][r] + bv[j]);
      }
    }
    __syncthreads();
    const int h0 = (n0 & (EMB - 1)) >> 6;  // first head of this block's 128 cols
    const int s0 = m0 >> 1;                // block's s base (128 rows per b)
    #pragma unroll
    for (int k = 0; k < 8; k++) {
      const int c = k * 512 + tid;         // 4096 16B-chunks: [256 rows][16 chunks]
      const int row = c >> 4, ch = c & 15;
      const int nl = row >> 1, bb = row & 1;
      const bf16x8 v = *reinterpret_cast<const bf16x8*>(T + nl * 264 + bb * 128 + ch * 8);
      const int hh = h0 + (nl >> 6), d = nl & 63;
      *reinterpret_cast<bf16x8*>(
          VTo + (((size_t)bb * NH + hh) * HD + d) * S_LEN + s0 + ch * 8) = v;
    }
  }
}

// ---------------- Flash attention (causal), bf16 MFMA, fixed-max softmax ----------------
// R0-verified structure (merged strip pair, double-buffered K/V in LDS,
// pad-72 P buffer, 1 barrier/tile). ROUND-12 (only change): s_setprio(1)
// around the QK^T and PV MFMA clusters — T5, measured +4-7% on attn (m191)
// in exactly this regime (multiple independent blocks/CU at different
// phases; NOT the m190 GEMM-lockstep null case). No structural change.

__global__ __launch_bounds__(256) void attn_kernel(
    const unsigned short* __restrict__ Q,
    const unsigned short* __restrict__ K,
    const unsigned short* __restrict__ VT,
    unsigned short* __restrict__ ctx) {
  const int bh = blockIdx.x;               // b*32+h
  const int p  = blockIdx.y;               // 0..7 strip pair
  const int tid = threadIdx.x;
  const int wave = tid >> 6, lane = tid & 63;
  const int lm = lane & 15, lq = lane >> 4;
  const int b = bh >> 5, h = bh & 31;
  const char* Qb8 = (const char*)(Q  + (size_t)bh * S_LEN * HD);
  const char* Kb8 = (const char*)(K  + (size_t)bh * S_LEN * HD);
  const char* Vb8 = (const char*)(VT + (size_t)bh * HD * S_LEN);

  __shared__ __align__(16) unsigned short Ks[2][2][64][32];  // [buf][half][row][32]
  __shared__ __align__(16) unsigned short Vs[2][2][64][32];
  __shared__ __align__(16) unsigned short Pbuf[4][32][72];
  unsigned short* Pw = &Pbuf[wave][0][0];

  const float C = 0.18033688011112042f;    // (1/8) * log2(e)
  const int q0A = p * 128, q0B = (15 - p) * 128;
  const int r0A = q0A + wave * 32, r0B = q0B + wave * 32;
  const int nt = (q0B >> 6) + 2;           // heavy strip's tile count

  const int srw = tid >> 2, sc16 = (tid & 3) * 16;

  bf16x8 qf[2][2][2];                      // [strip][i][ks]
  #pragma unroll
  for (int s = 0; s < 2; s++) {
    const int rr = (s == 0) ? r0A : r0B;
    #pragma unroll
    for (int i = 0; i < 2; i++)
      #pragma unroll
      for (int ks = 0; ks < 2; ks++)
        qf[s][i][ks] = *reinterpret_cast<const bf16x8*>(
            Qb8 + (size_t)(rr + i*16 + lm) * 128 + ks*64 + lq*16);
  }

  f32x4 O[2][2][4] = {};
  float l[2][2][4] = {};

  {
    char* kd = (char*)&Ks[0][0][0][0];
    char* vd = (char*)&Vs[0][0][0][0];
    async_copy16(Kb8 + (size_t)srw * 128      + sc16, kd        + tid*16);
    async_copy16(Kb8 + (size_t)srw * 128 + 64 + sc16, kd + 4096 + tid*16);
    async_copy16(Vb8 + (size_t)srw * 4096      + sc16, vd        + tid*16);
    async_copy16(Vb8 + (size_t)srw * 4096 + 64 + sc16, vd + 4096 + tid*16);
  }
  __syncthreads();

  for (int t = 0; t < nt; t++) {
    const int t0 = t * 64;
    const int buf = t & 1;

    if (t + 1 < nt) {
      const int t1 = t0 + 64;
      char* kd = (char*)&Ks[buf ^ 1][0][0][0];
      char* vd = (char*)&Vs[buf ^ 1][0][0][0];
      async_copy16(Kb8 + (size_t)(t1 + srw) * 128      + sc16, kd        + tid*16);
      async_copy16(Kb8 + (size_t)(t1 + srw) * 128 + 64 + sc16, kd + 4096 + tid*16);
      async_copy16(Vb8 + (size_t)srw * 4096 + t1*2      + sc16, vd        + tid*16);
      async_copy16(Vb8 + (size_t)srw * 4096 + t1*2 + 64 + sc16, vd + 4096 + tid*16);
    }

    const char* KsB = (const char*)&Ks[buf][0][0][0];
    const char* VsB = (const char*)&Vs[buf][0][0][0];

    #pragma unroll
    for (int s = 0; s < 2; s++) {
      const int rr = (s == 0) ? r0A : r0B;
      if (t0 <= rr + 31) {
        const bool clean = (t0 + 63 <= rr);
        const int jmax  = clean ? 4 : ((rr == t0) ? 2 : 4);
        const int kslim = clean ? 2 : ((rr == t0) ? 1 : 2);
        const int srow_c = rr + lq * 4;

        f32x4 sc[2][4] = {};
        #pragma unroll
        for (int ks = 0; ks < 2; ks++) {
          bf16x8 kf[4];
          #pragma unroll
          for (int j = 0; j < 4; j++)
            if (j < jmax)
              kf[j] = *reinterpret_cast<const bf16x8*>(
                  KsB + ks*4096 + (j*16 + lm)*64 + lq*16);
          __builtin_amdgcn_s_setprio(1);
          #pragma unroll
          for (int i = 0; i < 2; i++)
            #pragma unroll
            for (int j = 0; j < 4; j++)
              if (j < jmax)
                sc[i][j] = __builtin_amdgcn_mfma_f32_16x16x32_bf16(
                    qf[s][i][ks], kf[j], sc[i][j], 0, 0, 0);
          __builtin_amdgcn_s_setprio(0);
        }

        if (clean) {
          #pragma unroll
          for (int i = 0; i < 2; i++)
            #pragma unroll
            for (int j = 0; j < 4; j++)
              #pragma unroll
              for (int r = 0; r < 4; r++) {
                const float pe = EXP2F(sc[i][j][r] * C);
                l[s][i][r] += pe;
                Pw[(i*16 + lq*4 + r) * 72 + j*16 + lm] = f2bf(pe);
              }
        } else {
          #pragma unroll
          for (int i = 0; i < 2; i++)
            #pragma unroll
            for (int j = 0; j < 4; j++)
              if (j < jmax)
                #pragma unroll
                for (int r = 0; r < 4; r++) {
                  const int srow = srow_c + i*16 + r;
                  const int tcol = t0 + j*16 + lm;
                  const float pe = (tcol <= srow) ? EXP2F(sc[i][j][r] * C) : 0.0f;
                  l[s][i][r] += pe;
                  Pw[(i*16 + lq*4 + r) * 72 + j*16 + lm] = f2bf(pe);
                }
        }

        #pragma unroll
        for (int ks = 0; ks < 2; ks++) {
          if (ks < kslim) {
            bf16x8 pf[2], vf[4];
            #pragma unroll
            for (int i = 0; i < 2; i++)
              pf[i] = *reinterpret_cast<const bf16x8*>(Pw + (i*16 + lm)*72 + ks*32 + lq*8);
            #pragma unroll
            for (int j = 0; j < 4; j++)
              vf[j] = *reinterpret_cast<const bf16x8*>(
                  VsB + ks*4096 + (j*16 + lm)*64 + lq*16);
            __builtin_amdgcn_s_setprio(1);
            #pragma unroll
            for (int i = 0; i < 2; i++)
              #pragma unroll
              for (int j = 0; j < 4; j++)
                O[s][i][j] = __builtin_amdgcn_mfma_f32_16x16x32_bf16(
                    pf[i], vf[j], O[s][i][j], 0, 0, 0);
            __builtin_amdgcn_s_setprio(0);
          }
        }
      }
    }
    __syncthreads();
  }

  #pragma unroll
  for (int s = 0; s < 2; s++) {
    const int rr = (s == 0) ? r0A : r0B;
    #pragma unroll
    for (int i = 0; i < 2; i++) {
      #pragma unroll
      for (int r = 0; r < 4; r++) {
        float sum = l[s][i][r];
        sum += __shfl_xor(sum, 1, 64);
        sum += __shfl_xor(sum, 2, 64);
        sum += __shfl_xor(sum, 4, 64);
        sum += __shfl_xor(sum, 8, 64);
        const float inv = 1.0f / sum;
        const int srow = rr + lq*4 + i*16 + r;
        #pragma unroll
        for (int j = 0; j < 4; j++) {
          const int d = j*16 + lm;
          ctx[((size_t)srow * BATCH + b) * EMB + h*HD + d] = f2bf(O[s][i][j][r] * inv);
        }
      }
    }
  }
}

// ---------------- Output GEMM: R1 256x128 schedule, f32 + bias epilogue ----------------

__global__ __launch_bounds__(512, 2) void gemm_out(
    const unsigned short* __restrict__ A,
    const unsigned short* __restrict__ Wt,
    const float* __restrict__ bias,
    float* __restrict__ out) {
  extern __shared__ unsigned short lds[];
  const int tid = threadIdx.x;
  const int n0 = blockIdx.x * 128;
  const int m0 = blockIdx.y * 256;
  const int wave = tid >> 6, lane = tid & 63;
  const int wm = (wave >> 1) * 64, wn = (wave & 1) * 64;
  const int lm = lane & 15, lq = lane >> 4;
  const int K = 2048;
  const int NT = K / 64;

  const int srow = tid >> 3;
  const int gch  = (tid & 7) ^ (srow & 7);
  const unsigned short* Ab = A  + (size_t)(m0 + srow) * K + gch * 8;
  const unsigned short* Bb = Wt + (size_t)(n0 + srow) * K + gch * 8;

  auto stA = [&](int bufi, int k0, int rep) {
    async_copy16(Ab + (size_t)rep * 64 * K + k0,
                 lds + (size_t)bufi * TILE_SH + ((size_t)rep * 512 + tid) * 8);
  };
  auto stB = [&](int bufi, int k0, int rep) {
    async_copy16(Bb + (size_t)rep * 64 * K + k0,
                 lds + (size_t)bufi * TILE_SH + 16384 + ((size_t)rep * 512 + tid) * 8);
  };

  f32x4 acc[4][4] = {};

  stA(0, 0, 0); stA(0, 0, 1); stA(0, 0, 2); stA(0, 0, 3); stB(0, 0, 0); stB(0, 0, 1);
  stA(1, 64, 0); stA(1, 64, 1); stA(1, 64, 2); stA(1, 64, 3); stB(1, 64, 0); stB(1, 64, 1);
  asm volatile("s_waitcnt vmcnt(6)" ::: "memory");
  __builtin_amdgcn_s_barrier();

  int cur = 0;
  for (int t = 0; t < NT; t++) {
    const unsigned short* Abuf = lds + (size_t)cur * TILE_SH;
    const unsigned short* Bbuf = Abuf + 16384;
    const int pb = (cur >= 1) ? cur - 1 : 2;
    const int pk = (t + 2) * 64;
    const bool pre = (t + 2) < NT;

    bf16x8 b[4][2], a[2][2];
    #pragma unroll
    for (int j = 0; j < 4; j++) {
      const int R = wn + j * 16 + lm;
      #pragma unroll
      for (int ks = 0; ks < 2; ks++)
        b[j][ks] = *reinterpret_cast<const bf16x8*>(
            Bbuf + (size_t)R * 64 + (((ks * 4 + lq) ^ (R & 7)) * 8));
    }
    #pragma unroll
    for (int i = 0; i < 2; i++) {
      const int R = wm + i * 16 + lm;
      #pragma unroll
      for (int ks = 0; ks < 2; ks++)
        a[i][ks] = *reinterpret_cast<const bf16x8*>(
            Abuf + (size_t)R * 64 + (((ks * 4 + lq) ^ (R & 7)) * 8));
    }
    if (pre) { stA(pb, pk, 0); stA(pb, pk, 1); stB(pb, pk, 0); }
    __builtin_amdgcn_s_barrier();
    asm volatile("s_waitcnt lgkmcnt(0)" ::: "memory");
    __builtin_amdgcn_s_setprio(1);
    #pragma unroll
    for (int ks = 0; ks < 2; ks++)
      #pragma unroll
      for (int i = 0; i < 2; i++)
        #pragma unroll
        for (int j = 0; j < 4; j++)
          acc[i][j] = __builtin_amdgcn_mfma_f32_16x16x32_bf16(a[i][ks], b[j][ks], acc[i][j], 0, 0, 0);
    __builtin_amdgcn_s_setprio(0);
    __builtin_amdgcn_s_barrier();

    #pragma unroll
    for (int i = 0; i < 2; i++) {
      const int R = wm + (i + 2) * 16 + lm;
      #pragma unroll
      for (int ks = 0; ks < 2; ks++)
        a[i][ks] = *reinterpret_cast<const bf16x8*>(
            Abuf + (size_t)R * 64 + (((ks * 4 + lq) ^ (R & 7)) * 8));
    }
    if (pre) { stA(pb, pk, 2); stA(pb, pk, 3); stB(pb, pk, 1); }
    __builtin_amdgcn_s_barrier();
    asm volatile("s_waitcnt lgkmcnt(0)" ::: "memory");
    __builtin_amdgcn_s_setprio(1);
    #pragma unroll
    for (int ks = 0; ks < 2; ks++)
      #pragma unroll
      for (int i = 0; i < 2; i++)
        #pragma unroll
        for (int j = 0; j < 4; j++)
          acc[i + 2][j] = __builtin_amdgcn_mfma_f32_16x16x32_bf16(a[i][ks], b[j][ks], acc[i + 2][j], 0, 0, 0);
    __builtin_amdgcn_s_setprio(0);
    if (t + 1 < NT) {
      if (pre) asm volatile("s_waitcnt vmcnt(6)" ::: "memory");
      else     asm volatile("s_waitcnt vmcnt(0)" ::: "memory");
      __builtin_amdgcn_s_barrier();
    }
    cur = (cur == 2) ? 0 : cur + 1;
  }

  #pragma unroll
  for (int j = 0; j < 4; j++) {
    const int n = n0 + wn + j * 16 + lm;
    const float bv = bias[n];
    #pragma unroll
    for (int i = 0; i < 4; i++) {
      #pragma unroll
      for (int r = 0; r < 4; r++) {
        const int m = m0 + wm + i * 16 + lq * 4 + r;
        out[(size_t)m * EMB + n] = acc[i][j][r] + bv;
      }
    }
  }
}

// ---------------- host launcher ----------------

extern "C" void kernel_launch(void* const* d_in, const int* in_sizes, int n_in,
                              void* d_out, int out_size, void* d_ws, size_t ws_size,
                              hipStream_t stream) {
  const float* hidden = (const float*)d_in[0];
  const float* qkv_w  = (const float*)d_in[1];
  const float* qkv_b  = (const float*)d_in[2];
  const float* out_w  = (const float*)d_in[3];
  const float* out_b  = (const float*)d_in[4];
  float* out = (float*)d_out;

  static bool attr_set = false;
  if (!attr_set) {
    hipFuncSetAttribute(reinterpret_cast<const void*>(gemm_qkv),
                        hipFuncAttributeMaxDynamicSharedMemorySize, GEMM_LDS_BYTES);
    hipFuncSetAttribute(reinterpret_cast<const void*>(gemm_out),
                        hipFuncAttributeMaxDynamicSharedMemorySize, GEMM_LDS_BYTES);
    attr_set = true;
  }

  unsigned short* ws = (unsigned short*)d_ws;
  unsigned short* hbf   = ws;                                  // 4096*2048
  unsigned short* qkvwT = hbf   + (size_t)M_ROWS * EMB;        // 6144*2048
  unsigned short* outwT = qkvwT + (size_t)QKV_N * EMB;         // 2048*2048
  unsigned short* Qb    = outwT + (size_t)EMB * EMB;           // 64*2048*64 each
  unsigned short* Kb    = Qb    + (size_t)64 * S_LEN * HD;
  unsigned short* VTb   = Kb    + (size_t)64 * S_LEN * HD;
  unsigned short* ctx   = VTb   + (size_t)64 * S_LEN * HD;     // 4096*2048

  // 1. single prep launch: cast + both weight transposes
  prep_all<<<PREP_BLKS, 256, 0, stream>>>(hidden, hbf, qkv_w, qkvwT, out_w, outwT);

  // 2. fused QKV projection + bias + RoPE + scatter; V written directly as VT
  gemm_qkv<<<dim3(QKV_N / 128, M_ROWS / 256), 512, GEMM_LDS_BYTES, stream>>>(
      hbf, qkvwT, qkv_b, Qb, Kb, VTb);

  // 3. causal flash attention (R0 merged-strip structure + T5 setprio)
  attn_kernel<<<dim3(64, 8), 256, 0, stream>>>(Qb, Kb, VTb, ctx);

  // 4. output projection
  gemm_out<<<dim3(EMB / 128, M_ROWS / 256), 512, GEMM_LDS_BYTES, stream>>>(
      ctx, outwT, out_b, out);
}

// Round 13
// 343.577 us; speedup vs baseline: 1.0605x; 1.0605x over previous
//
#include <hip/hip_runtime.h>
#include <hip/hip_bf16.h>

// Problem constants (S=2048, B=2, E=2048, H=32, D=64)
#define S_LEN 2048
#define BATCH 2
#define EMB   2048
#define NH    32
#define HD    64
#define M_ROWS (S_LEN * BATCH)   // 4096
#define QKV_N  (3 * EMB)         // 6144

typedef short bf16x8 __attribute__((ext_vector_type(8)));
typedef float f32x4  __attribute__((ext_vector_type(4)));

__device__ __forceinline__ unsigned short f2bf(float f) {
  unsigned int u = __float_as_uint(f);
  u += 0x7fffu + ((u >> 16) & 1u);       // round-to-nearest-even
  return (unsigned short)(u >> 16);
}
__device__ __forceinline__ float bf2f(unsigned short h) {
  return __uint_as_float(((unsigned int)h) << 16);
}
__device__ __forceinline__ void async_copy16(const void* g, void* lds_d) {
  __builtin_amdgcn_global_load_lds(
      (const __attribute__((address_space(1))) void*)g,
      (__attribute__((address_space(3))) void*)lds_d, 16, 0, 0);
}

#if __has_builtin(__builtin_amdgcn_exp2f)
#define EXP2F(x) __builtin_amdgcn_exp2f(x)
#else
#define EXP2F(x) __expf((x) * 0.6931471805599453f)
#endif

// ---------------- prep: ONE launch for cast + both weight transposes ----------------
// Merging the 3 independent prep kernels into one flat-grid launch removes 2
// inter-launch gaps (R7-measured win). ~20 us vs ~23 us HBM-BW floor for its
// 144 MB of traffic -> at roofline.

#define CAST_BLKS  (M_ROWS * EMB / 4 / 256)          // 8192
#define TCQ_BX     (QKV_N / 64)                      // 96
#define TCQ_BLKS   (TCQ_BX * (EMB / 64))             // 3072
#define TCO_BX     (EMB / 64)                        // 32
#define TCO_BLKS   (TCO_BX * (EMB / 64))             // 1024
#define PREP_BLKS  (CAST_BLKS + TCQ_BLKS + TCO_BLKS) // 12288

__device__ __forceinline__ void transpose_body(
    const float* __restrict__ in, unsigned short* __restrict__ out,
    int R, int C, int bx, int by, int tid) {
  __shared__ unsigned short t[64][65];
  const int bc = bx * 64, br = by * 64;
  const int tx = tid & 63, ty = tid >> 6;   // ty 0..3
  #pragma unroll
  for (int rr = ty; rr < 64; rr += 4)
    t[rr][tx] = f2bf(in[(size_t)(br + rr) * C + bc + tx]);
  __syncthreads();
  #pragma unroll
  for (int rr = ty; rr < 64; rr += 4)
    out[(size_t)(bc + rr) * R + br + tx] = t[tx][rr];
}

__global__ __launch_bounds__(256) void prep_all(
    const float* __restrict__ hidden, unsigned short* __restrict__ hbf,
    const float* __restrict__ qkv_w, unsigned short* __restrict__ qkvwT,
    const float* __restrict__ out_w, unsigned short* __restrict__ outwT) {
  const int bid = blockIdx.x, tid = threadIdx.x;
  if (bid < CAST_BLKS) {
    const int i = bid * 256 + tid;
    float4 v = reinterpret_cast<const float4*>(hidden)[i];
    ushort4 o;
    o.x = f2bf(v.x); o.y = f2bf(v.y); o.z = f2bf(v.z); o.w = f2bf(v.w);
    reinterpret_cast<ushort4*>(hbf)[i] = o;
  } else if (bid < CAST_BLKS + TCQ_BLKS) {
    const int b = bid - CAST_BLKS;
    transpose_body(qkv_w, qkvwT, EMB, QKV_N, b % TCQ_BX, b / TCQ_BX, tid);
  } else {
    const int b = bid - CAST_BLKS - TCQ_BLKS;
    transpose_body(out_w, outwT, EMB, EMB, b % TCO_BX, b / TCO_BX, tid);
  }
}

// ---------------- QKV GEMM (measured-best): 256x128 tile, BK=64, 8 waves,
// triple-buffered LDS, 2 phases/K-tile with counted vmcnt + setprio.
// 112.7-116 us ~= 890-916 TF = the documented ceiling of this structural
// family (m97-class 2-barrier loop). V-block (which==2) epilogue writes
// VT[b,h,d,s] DIRECTLY via LDS transpose -> transpose_v kernel eliminated.

constexpr int TILE_SH = 24576;                 // shorts/buffer: A 256x64 + B 128x64
constexpr int GEMM_LDS_BYTES = 3 * TILE_SH * 2; // 147456 B

__global__ __launch_bounds__(512, 2) void gemm_qkv(
    const unsigned short* __restrict__ A,
    const unsigned short* __restrict__ Wt,
    const float* __restrict__ bias,
    unsigned short* __restrict__ Qo,
    unsigned short* __restrict__ Ko,
    unsigned short* __restrict__ VTo) {
  extern __shared__ unsigned short lds[];
  const int tid = threadIdx.x;               // 0..511
  const int n0 = blockIdx.x * 128;
  const int m0 = blockIdx.y * 256;
  const int wave = tid >> 6, lane = tid & 63;
  const int wm = (wave >> 1) * 64, wn = (wave & 1) * 64;   // 4M x 2N waves
  const int lm = lane & 15, lq = lane >> 4;
  const int K = 2048;
  const int NT = K / 64;                     // 32 K-tiles

  const int srow = tid >> 3;                 // 0..63
  const int gch  = (tid & 7) ^ (srow & 7);
  const unsigned short* Ab = A  + (size_t)(m0 + srow) * K + gch * 8;
  const unsigned short* Bb = Wt + (size_t)(n0 + srow) * K + gch * 8;

  auto stA = [&](int bufi, int k0, int rep) {
    async_copy16(Ab + (size_t)rep * 64 * K + k0,
                 lds + (size_t)bufi * TILE_SH + ((size_t)rep * 512 + tid) * 8);
  };
  auto stB = [&](int bufi, int k0, int rep) {
    async_copy16(Bb + (size_t)rep * 64 * K + k0,
                 lds + (size_t)bufi * TILE_SH + 16384 + ((size_t)rep * 512 + tid) * 8);
  };

  f32x4 acc[4][4] = {};

  stA(0, 0, 0); stA(0, 0, 1); stA(0, 0, 2); stA(0, 0, 3); stB(0, 0, 0); stB(0, 0, 1);
  stA(1, 64, 0); stA(1, 64, 1); stA(1, 64, 2); stA(1, 64, 3); stB(1, 64, 0); stB(1, 64, 1);
  asm volatile("s_waitcnt vmcnt(6)" ::: "memory");
  __builtin_amdgcn_s_barrier();

  int cur = 0;
  for (int t = 0; t < NT; t++) {
    const unsigned short* Abuf = lds + (size_t)cur * TILE_SH;
    const unsigned short* Bbuf = Abuf + 16384;
    const int pb = (cur >= 1) ? cur - 1 : 2;   // (cur+2)%3
    const int pk = (t + 2) * 64;
    const bool pre = (t + 2) < NT;

    bf16x8 b[4][2], a[2][2];
    #pragma unroll
    for (int j = 0; j < 4; j++) {
      const int R = wn + j * 16 + lm;
      #pragma unroll
      for (int ks = 0; ks < 2; ks++)
        b[j][ks] = *reinterpret_cast<const bf16x8*>(
            Bbuf + (size_t)R * 64 + (((ks * 4 + lq) ^ (R & 7)) * 8));
    }
    #pragma unroll
    for (int i = 0; i < 2; i++) {
      const int R = wm + i * 16 + lm;
      #pragma unroll
      for (int ks = 0; ks < 2; ks++)
        a[i][ks] = *reinterpret_cast<const bf16x8*>(
            Abuf + (size_t)R * 64 + (((ks * 4 + lq) ^ (R & 7)) * 8));
    }
    if (pre) { stA(pb, pk, 0); stA(pb, pk, 1); stB(pb, pk, 0); }
    __builtin_amdgcn_s_barrier();
    asm volatile("s_waitcnt lgkmcnt(0)" ::: "memory");
    __builtin_amdgcn_s_setprio(1);
    #pragma unroll
    for (int ks = 0; ks < 2; ks++)
      #pragma unroll
      for (int i = 0; i < 2; i++)
        #pragma unroll
        for (int j = 0; j < 4; j++)
          acc[i][j] = __builtin_amdgcn_mfma_f32_16x16x32_bf16(a[i][ks], b[j][ks], acc[i][j], 0, 0, 0);
    __builtin_amdgcn_s_setprio(0);
    __builtin_amdgcn_s_barrier();

    #pragma unroll
    for (int i = 0; i < 2; i++) {
      const int R = wm + (i + 2) * 16 + lm;
      #pragma unroll
      for (int ks = 0; ks < 2; ks++)
        a[i][ks] = *reinterpret_cast<const bf16x8*>(
            Abuf + (size_t)R * 64 + (((ks * 4 + lq) ^ (R & 7)) * 8));
    }
    if (pre) { stA(pb, pk, 2); stA(pb, pk, 3); stB(pb, pk, 1); }
    __builtin_amdgcn_s_barrier();
    asm volatile("s_waitcnt lgkmcnt(0)" ::: "memory");
    __builtin_amdgcn_s_setprio(1);
    #pragma unroll
    for (int ks = 0; ks < 2; ks++)
      #pragma unroll
      for (int i = 0; i < 2; i++)
        #pragma unroll
        for (int j = 0; j < 4; j++)
          acc[i + 2][j] = __builtin_amdgcn_mfma_f32_16x16x32_bf16(a[i][ks], b[j][ks], acc[i + 2][j], 0, 0, 0);
    __builtin_amdgcn_s_setprio(0);
    if (t + 1 < NT) {
      if (pre) asm volatile("s_waitcnt vmcnt(6)" ::: "memory");
      else     asm volatile("s_waitcnt vmcnt(0)" ::: "memory");
      __builtin_amdgcn_s_barrier();
    }
    cur = (cur == 2) ? 0 : cur + 1;
  }

  // epilogue
  const int which = n0 >> 11;   // 0=q 1=k 2=v, uniform per block
  float bv[4];
  #pragma unroll
  for (int j = 0; j < 4; j++) bv[j] = bias[n0 + wn + j * 16 + lm];

  if (which < 2) {
    unsigned short* dst = (which == 0) ? Qo : Ko;
    // RoPE pairs (d, d+32) = (acc[i][j], acc[i][j+2]) for j=0,1 (d = j*16+lm)
    #pragma unroll
    for (int j = 0; j < 2; j++) {
      const int n = n0 + wn + j * 16 + lm;
      const int e = n & (EMB - 1), h = e >> 6, d = e & 63;   // d < 32
      const float invf = EXP2F((float)d * -0.4152410118609203f);  // 10000^(-d/32)
      #pragma unroll
      for (int i = 0; i < 4; i++) {
        #pragma unroll
        for (int r = 0; r < 4; r++) {
          const int m = m0 + wm + i * 16 + lq * 4 + r;
          const int s = m >> 1, b = m & 1;
          const float v1 = acc[i][j][r]     + bv[j];
          const float v2 = acc[i][j + 2][r] + bv[j + 2];
          float sn, cs;
          __sincosf((float)s * invf, &sn, &cs);
          const size_t base = (((size_t)b * NH + h) * S_LEN + s) * HD + d;
          dst[base]      = f2bf(v1 * cs - v2 * sn);
          dst[base + 32] = f2bf(v2 * cs + v1 * sn);
        }
      }
    }
  } else {
    // V: route tile through LDS -> write VT[b,h,d,s] with coalesced s-major stores.
    __syncthreads();                       // K-loop LDS now dead everywhere
    unsigned short* T = lds;
    #pragma unroll
    for (int j = 0; j < 4; j++) {
      const int nl = wn + j * 16 + lm;
      #pragma unroll
      for (int i = 0; i < 4; i++) {
        const int sbase = (wm >> 1) + i * 8 + lq * 2;   // s_local of r=0/1
        #pragma unroll
        for (int r = 0; r < 4; r++)
          T[nl * 264 + (r & 1) * 128 + sbase + (r >> 1)] = f2bf(acc[i][j][r] + bv[j]);
      }
    }
    __syncthreads();
    const int h0 = (n0 & (EMB - 1)) >> 6;  // first head of this block's 128 cols
    const int s0 = m0 >> 1;                // block's s base (128 rows per b)
    #pragma unroll
    for (int k = 0; k < 8; k++) {
      const int c = k * 512 + tid;         // 4096 16B-chunks: [256 rows][16 chunks]
      const int row = c >> 4, ch = c & 15;
      const int nl = row >> 1, bb = row & 1;
      const bf16x8 v = *reinterpret_cast<const bf16x8*>(T + nl * 264 + bb * 128 + ch * 8);
      const int hh = h0 + (nl >> 6), d = nl & 63;
      *reinterpret_cast<bf16x8*>(
          VTo + (((size_t)bb * NH + hh) * HD + d) * S_LEN + s0 + ch * 8) = v;
    }
  }
}

// ---------------- Flash attention (causal), bf16 MFMA, fixed-max softmax ----------------
// R0-verified structure (merged strip pair, double-buffered K/V in LDS,
// pad-72 P buffer, 1 barrier/tile). Session evidence: six variants
// (V-direct, 8-wave strip-split, P-swizzle, in-register P via shfl, 64-row
// strips, MFMA setprio) each measured slower or null. Accepted local optimum.

__global__ __launch_bounds__(256) void attn_kernel(
    const unsigned short* __restrict__ Q,
    const unsigned short* __restrict__ K,
    const unsigned short* __restrict__ VT,
    unsigned short* __restrict__ ctx) {
  const int bh = blockIdx.x;               // b*32+h
  const int p  = blockIdx.y;               // 0..7 strip pair
  const int tid = threadIdx.x;
  const int wave = tid >> 6, lane = tid & 63;
  const int lm = lane & 15, lq = lane >> 4;
  const int b = bh >> 5, h = bh & 31;
  const char* Qb8 = (const char*)(Q  + (size_t)bh * S_LEN * HD);
  const char* Kb8 = (const char*)(K  + (size_t)bh * S_LEN * HD);
  const char* Vb8 = (const char*)(VT + (size_t)bh * HD * S_LEN);

  __shared__ __align__(16) unsigned short Ks[2][2][64][32];  // [buf][half][row][32]
  __shared__ __align__(16) unsigned short Vs[2][2][64][32];
  __shared__ __align__(16) unsigned short Pbuf[4][32][72];
  unsigned short* Pw = &Pbuf[wave][0][0];

  const float C = 0.18033688011112042f;    // (1/8) * log2(e)
  const int q0A = p * 128, q0B = (15 - p) * 128;
  const int r0A = q0A + wave * 32, r0B = q0B + wave * 32;
  const int nt = (q0B >> 6) + 2;           // heavy strip's tile count

  const int srw = tid >> 2, sc16 = (tid & 3) * 16;

  bf16x8 qf[2][2][2];                      // [strip][i][ks]
  #pragma unroll
  for (int s = 0; s < 2; s++) {
    const int rr = (s == 0) ? r0A : r0B;
    #pragma unroll
    for (int i = 0; i < 2; i++)
      #pragma unroll
      for (int ks = 0; ks < 2; ks++)
        qf[s][i][ks] = *reinterpret_cast<const bf16x8*>(
            Qb8 + (size_t)(rr + i*16 + lm) * 128 + ks*64 + lq*16);
  }

  f32x4 O[2][2][4] = {};
  float l[2][2][4] = {};

  {
    char* kd = (char*)&Ks[0][0][0][0];
    char* vd = (char*)&Vs[0][0][0][0];
    async_copy16(Kb8 + (size_t)srw * 128      + sc16, kd        + tid*16);
    async_copy16(Kb8 + (size_t)srw * 128 + 64 + sc16, kd + 4096 + tid*16);
    async_copy16(Vb8 + (size_t)srw * 4096      + sc16, vd        + tid*16);
    async_copy16(Vb8 + (size_t)srw * 4096 + 64 + sc16, vd + 4096 + tid*16);
  }
  __syncthreads();

  for (int t = 0; t < nt; t++) {
    const int t0 = t * 64;
    const int buf = t & 1;

    if (t + 1 < nt) {
      const int t1 = t0 + 64;
      char* kd = (char*)&Ks[buf ^ 1][0][0][0];
      char* vd = (char*)&Vs[buf ^ 1][0][0][0];
      async_copy16(Kb8 + (size_t)(t1 + srw) * 128      + sc16, kd        + tid*16);
      async_copy16(Kb8 + (size_t)(t1 + srw) * 128 + 64 + sc16, kd + 4096 + tid*16);
      async_copy16(Vb8 + (size_t)srw * 4096 + t1*2      + sc16, vd        + tid*16);
      async_copy16(Vb8 + (size_t)srw * 4096 + t1*2 + 64 + sc16, vd + 4096 + tid*16);
    }

    const char* KsB = (const char*)&Ks[buf][0][0][0];
    const char* VsB = (const char*)&Vs[buf][0][0][0];

    #pragma unroll
    for (int s = 0; s < 2; s++) {
      const int rr = (s == 0) ? r0A : r0B;
      if (t0 <= rr + 31) {
        const bool clean = (t0 + 63 <= rr);
        const int jmax  = clean ? 4 : ((rr == t0) ? 2 : 4);
        const int kslim = clean ? 2 : ((rr == t0) ? 1 : 2);
        const int srow_c = rr + lq * 4;

        f32x4 sc[2][4] = {};
        #pragma unroll
        for (int ks = 0; ks < 2; ks++) {
          bf16x8 kf[4];
          #pragma unroll
          for (int j = 0; j < 4; j++)
            if (j < jmax)
              kf[j] = *reinterpret_cast<const bf16x8*>(
                  KsB + ks*4096 + (j*16 + lm)*64 + lq*16);
          #pragma unroll
          for (int i = 0; i < 2; i++)
            #pragma unroll
            for (int j = 0; j < 4; j++)
              if (j < jmax)
                sc[i][j] = __builtin_amdgcn_mfma_f32_16x16x32_bf16(
                    qf[s][i][ks], kf[j], sc[i][j], 0, 0, 0);
        }

        if (clean) {
          #pragma unroll
          for (int i = 0; i < 2; i++)
            #pragma unroll
            for (int j = 0; j < 4; j++)
              #pragma unroll
              for (int r = 0; r < 4; r++) {
                const float pe = EXP2F(sc[i][j][r] * C);
                l[s][i][r] += pe;
                Pw[(i*16 + lq*4 + r) * 72 + j*16 + lm] = f2bf(pe);
              }
        } else {
          #pragma unroll
          for (int i = 0; i < 2; i++)
            #pragma unroll
            for (int j = 0; j < 4; j++)
              if (j < jmax)
                #pragma unroll
                for (int r = 0; r < 4; r++) {
                  const int srow = srow_c + i*16 + r;
                  const int tcol = t0 + j*16 + lm;
                  const float pe = (tcol <= srow) ? EXP2F(sc[i][j][r] * C) : 0.0f;
                  l[s][i][r] += pe;
                  Pw[(i*16 + lq*4 + r) * 72 + j*16 + lm] = f2bf(pe);
                }
        }

        #pragma unroll
        for (int ks = 0; ks < 2; ks++) {
          if (ks < kslim) {
            bf16x8 pf[2], vf[4];
            #pragma unroll
            for (int i = 0; i < 2; i++)
              pf[i] = *reinterpret_cast<const bf16x8*>(Pw + (i*16 + lm)*72 + ks*32 + lq*8);
            #pragma unroll
            for (int j = 0; j < 4; j++)
              vf[j] = *reinterpret_cast<const bf16x8*>(
                  VsB + ks*4096 + (j*16 + lm)*64 + lq*16);
            #pragma unroll
            for (int i = 0; i < 2; i++)
              #pragma unroll
              for (int j = 0; j < 4; j++)
                O[s][i][j] = __builtin_amdgcn_mfma_f32_16x16x32_bf16(
                    pf[i], vf[j], O[s][i][j], 0, 0, 0);
          }
        }
      }
    }
    __syncthreads();
  }

  #pragma unroll
  for (int s = 0; s < 2; s++) {
    const int rr = (s == 0) ? r0A : r0B;
    #pragma unroll
    for (int i = 0; i < 2; i++) {
      #pragma unroll
      for (int r = 0; r < 4; r++) {
        float sum = l[s][i][r];
        sum += __shfl_xor(sum, 1, 64);
        sum += __shfl_xor(sum, 2, 64);
        sum += __shfl_xor(sum, 4, 64);
        sum += __shfl_xor(sum, 8, 64);
        const float inv = 1.0f / sum;
        const int srow = rr + lq*4 + i*16 + r;
        #pragma unroll
        for (int j = 0; j < 4; j++) {
          const int d = j*16 + lm;
          ctx[((size_t)srow * BATCH + b) * EMB + h*HD + d] = f2bf(O[s][i][j][r] * inv);
        }
      }
    }
  }
}

// ---------------- Output GEMM: same 256x128 schedule, f32 + bias epilogue ----------------

__global__ __launch_bounds__(512, 2) void gemm_out(
    const unsigned short* __restrict__ A,
    const unsigned short* __restrict__ Wt,
    const float* __restrict__ bias,
    float* __restrict__ out) {
  extern __shared__ unsigned short lds[];
  const int tid = threadIdx.x;
  const int n0 = blockIdx.x * 128;
  const int m0 = blockIdx.y * 256;
  const int wave = tid >> 6, lane = tid & 63;
  const int wm = (wave >> 1) * 64, wn = (wave & 1) * 64;
  const int lm = lane & 15, lq = lane >> 4;
  const int K = 2048;
  const int NT = K / 64;

  const int srow = tid >> 3;
  const int gch  = (tid & 7) ^ (srow & 7);
  const unsigned short* Ab = A  + (size_t)(m0 + srow) * K + gch * 8;
  const unsigned short* Bb = Wt + (size_t)(n0 + srow) * K + gch * 8;

  auto stA = [&](int bufi, int k0, int rep) {
    async_copy16(Ab + (size_t)rep * 64 * K + k0,
                 lds + (size_t)bufi * TILE_SH + ((size_t)rep * 512 + tid) * 8);
  };
  auto stB = [&](int bufi, int k0, int rep) {
    async_copy16(Bb + (size_t)rep * 64 * K + k0,
                 lds + (size_t)bufi * TILE_SH + 16384 + ((size_t)rep * 512 + tid) * 8);
  };

  f32x4 acc[4][4] = {};

  stA(0, 0, 0); stA(0, 0, 1); stA(0, 0, 2); stA(0, 0, 3); stB(0, 0, 0); stB(0, 0, 1);
  stA(1, 64, 0); stA(1, 64, 1); stA(1, 64, 2); stA(1, 64, 3); stB(1, 64, 0); stB(1, 64, 1);
  asm volatile("s_waitcnt vmcnt(6)" ::: "memory");
  __builtin_amdgcn_s_barrier();

  int cur = 0;
  for (int t = 0; t < NT; t++) {
    const unsigned short* Abuf = lds + (size_t)cur * TILE_SH;
    const unsigned short* Bbuf = Abuf + 16384;
    const int pb = (cur >= 1) ? cur - 1 : 2;
    const int pk = (t + 2) * 64;
    const bool pre = (t + 2) < NT;

    bf16x8 b[4][2], a[2][2];
    #pragma unroll
    for (int j = 0; j < 4; j++) {
      const int R = wn + j * 16 + lm;
      #pragma unroll
      for (int ks = 0; ks < 2; ks++)
        b[j][ks] = *reinterpret_cast<const bf16x8*>(
            Bbuf + (size_t)R * 64 + (((ks * 4 + lq) ^ (R & 7)) * 8));
    }
    #pragma unroll
    for (int i = 0; i < 2; i++) {
      const int R = wm + i * 16 + lm;
      #pragma unroll
      for (int ks = 0; ks < 2; ks++)
        a[i][ks] = *reinterpret_cast<const bf16x8*>(
            Abuf + (size_t)R * 64 + (((ks * 4 + lq) ^ (R & 7)) * 8));
    }
    if (pre) { stA(pb, pk, 0); stA(pb, pk, 1); stB(pb, pk, 0); }
    __builtin_amdgcn_s_barrier();
    asm volatile("s_waitcnt lgkmcnt(0)" ::: "memory");
    __builtin_amdgcn_s_setprio(1);
    #pragma unroll
    for (int ks = 0; ks < 2; ks++)
      #pragma unroll
      for (int i = 0; i < 2; i++)
        #pragma unroll
        for (int j = 0; j < 4; j++)
          acc[i][j] = __builtin_amdgcn_mfma_f32_16x16x32_bf16(a[i][ks], b[j][ks], acc[i][j], 0, 0, 0);
    __builtin_amdgcn_s_setprio(0);
    __builtin_amdgcn_s_barrier();

    #pragma unroll
    for (int i = 0; i < 2; i++) {
      const int R = wm + (i + 2) * 16 + lm;
      #pragma unroll
      for (int ks = 0; ks < 2; ks++)
        a[i][ks] = *reinterpret_cast<const bf16x8*>(
            Abuf + (size_t)R * 64 + (((ks * 4 + lq) ^ (R & 7)) * 8));
    }
    if (pre) { stA(pb, pk, 2); stA(pb, pk, 3); stB(pb, pk, 1); }
    __builtin_amdgcn_s_barrier();
    asm volatile("s_waitcnt lgkmcnt(0)" ::: "memory");
    __builtin_amdgcn_s_setprio(1);
    #pragma unroll
    for (int ks = 0; ks < 2; ks++)
      #pragma unroll
      for (int i = 0; i < 2; i++)
        #pragma unroll
        for (int j = 0; j < 4; j++)
          acc[i + 2][j] = __builtin_amdgcn_mfma_f32_16x16x32_bf16(a[i][ks], b[j][ks], acc[i + 2][j], 0, 0, 0);
    __builtin_amdgcn_s_setprio(0);
    if (t + 1 < NT) {
      if (pre) asm volatile("s_waitcnt vmcnt(6)" ::: "memory");
      else     asm volatile("s_waitcnt vmcnt(0)" ::: "memory");
      __builtin_amdgcn_s_barrier();
    }
    cur = (cur == 2) ? 0 : cur + 1;
  }

  #pragma unroll
  for (int j = 0; j < 4; j++) {
    const int n = n0 + wn + j * 16 + lm;
    const float bv = bias[n];
    #pragma unroll
    for (int i = 0; i < 4; i++) {
      #pragma unroll
      for (int r = 0; r < 4; r++) {
        const int m = m0 + wm + i * 16 + lq * 4 + r;
        out[(size_t)m * EMB + n] = acc[i][j][r] + bv;
      }
    }
  }
}

// ---------------- host launcher ----------------

extern "C" void kernel_launch(void* const* d_in, const int* in_sizes, int n_in,
                              void* d_out, int out_size, void* d_ws, size_t ws_size,
                              hipStream_t stream) {
  const float* hidden = (const float*)d_in[0];
  const float* qkv_w  = (const float*)d_in[1];
  const float* qkv_b  = (const float*)d_in[2];
  const float* out_w  = (const float*)d_in[3];
  const float* out_b  = (const float*)d_in[4];
  float* out = (float*)d_out;

  static bool attr_set = false;
  if (!attr_set) {
    hipFuncSetAttribute(reinterpret_cast<const void*>(gemm_qkv),
                        hipFuncAttributeMaxDynamicSharedMemorySize, GEMM_LDS_BYTES);
    hipFuncSetAttribute(reinterpret_cast<const void*>(gemm_out),
                        hipFuncAttributeMaxDynamicSharedMemorySize, GEMM_LDS_BYTES);
    attr_set = true;
  }

  unsigned short* ws = (unsigned short*)d_ws;
  unsigned short* hbf   = ws;                                  // 4096*2048
  unsigned short* qkvwT = hbf   + (size_t)M_ROWS * EMB;        // 6144*2048
  unsigned short* outwT = qkvwT + (size_t)QKV_N * EMB;         // 2048*2048
  unsigned short* Qb    = outwT + (size_t)EMB * EMB;           // 64*2048*64 each
  unsigned short* Kb    = Qb    + (size_t)64 * S_LEN * HD;
  unsigned short* VTb   = Kb    + (size_t)64 * S_LEN * HD;
  unsigned short* ctx   = VTb   + (size_t)64 * S_LEN * HD;     // 4096*2048

  // 1. single prep launch: cast + both weight transposes
  prep_all<<<PREP_BLKS, 256, 0, stream>>>(hidden, hbf, qkv_w, qkvwT, out_w, outwT);

  // 2. fused QKV projection + bias + RoPE + scatter; V written directly as VT
  gemm_qkv<<<dim3(QKV_N / 128, M_ROWS / 256), 512, GEMM_LDS_BYTES, stream>>>(
      hbf, qkvwT, qkv_b, Qb, Kb, VTb);

  // 3. causal flash attention (R0-exact merged-strip structure)
  attn_kernel<<<dim3(64, 8), 256, 0, stream>>>(Qb, Kb, VTb, ctx);

  // 4. output projection
  gemm_out<<<dim3(EMB / 128, M_ROWS / 256), 512, GEMM_LDS_BYTES, stream>>>(
      ctx, outwT, out_b, out);
}